// Round 19
// baseline (118.290 us; speedup 1.0000x reference)
//
#include <hip/hip_runtime.h>

typedef _Float16 f16;
typedef _Float16 f16x8 __attribute__((ext_vector_type(8)));
typedef __fp16 hf16x2 __attribute__((ext_vector_type(2)));
typedef float f32x4 __attribute__((ext_vector_type(4)));
typedef float f32x16 __attribute__((ext_vector_type(16)));

// ---------------- d_ws layout (32x32x16 MFMA fragment order) ----------------
// [0, 262144) : f16 weight images, per-lane A-fragment order for
//   mfma_f32_32x32x16_f16. frag f = T*nks + m at imgbase + (f*64+lane)*16 + j*2
//   holds W[k_logical][och_out = 32T + (lane&31)], natural k_raw = 16m +
//   8*(lane>>5) + j.
//     k_logical = k_raw          for L1 (input built raw by L0)
//     k_logical = klog32(k_raw)  for L2..L7, C0, C1, C2 (in-register chaining;
//       C row=(reg&3)+8*(reg>>2)+4*(lane>>5) vs B k=8*(lane>>5)+j mismatch is
//       exactly a swap of bits 2<->3 of the within-16 k index)
//   L1..L7 (128x128, nks=8): i*32768 | C0h (64x128): 229376
//   C1 (64x64, nks=4): 245760 | C2: 253952
// [262144, +10240) : fp32 params block (identical to R11..R18):
//   0 b0f[128] | 128 W0p[3][128] | 512 b5f[128] | 640 W5p[3][128]
//   1024 db1 1152 db2 1280 db3 1408 db4 1536 db6 1664 db7 (x128)
//   1792 cb0[64] | 1856 cWv[3][64] | 2048 cb1[64] | 2112 cb2[64]
//   2176 sW[128] | 2304 sb | 2308 rWT[3][64] | 2500 rb[3]
#define WS_PARAMS 262144

struct Ptrs { const float* p[29]; };

__device__ __forceinline__ int klog32(int q) {
  return (q & ~12) | ((q & 4) << 1) | ((q & 8) >> 1);
}

// ---------------------------------------------------------------------------
// Prepass (verbatim from passing R17/R18)
// ---------------------------------------------------------------------------
__global__ void nerf_prep(Ptrs ptrs, char* __restrict__ ws) {
  const int t = threadIdx.x;
  if (blockIdx.x == 0) {
    float* P = (float*)(ws + WS_PARAMS);
    const float* cond = ptrs.p[1];
    const float* dW0 = ptrs.p[3];  const float* db0 = ptrs.p[4];
    const float* dW5 = ptrs.p[13]; const float* db5 = ptrs.p[14];
    if (t < 128) {
      float a0 = db0[t], a5 = db5[t];
      for (int k = 0; k < 64; ++k) {
        const float c = cond[k];
        a0 += c * dW0[(3 + k) * 128 + t];
        a5 += c * dW5[(3 + k) * 128 + t];
      }
      P[t] = a0;          // b0f
      P[512 + t] = a5;    // b5f
      for (int k = 0; k < 3; ++k) {
        P[128 + k * 128 + t] = dW0[k * 128 + t];   // W0p
        P[640 + k * 128 + t] = dW5[k * 128 + t];   // W5p
      }
      P[1024 + t] = ptrs.p[6][t];    // db1
      P[1152 + t] = ptrs.p[8][t];    // db2
      P[1280 + t] = ptrs.p[10][t];   // db3
      P[1408 + t] = ptrs.p[12][t];   // db4
      P[1536 + t] = ptrs.p[16][t];   // db6
      P[1664 + t] = ptrs.p[18][t];   // db7
      P[2176 + t] = ptrs.p[19][t];   // sW
    }
    if (t < 64) {
      P[1792 + t] = ptrs.p[22][t];   // cb0
      for (int k = 0; k < 3; ++k)    // cWv = cW0 rows 128..130
        P[1856 + k * 64 + t] = ptrs.p[21][(128 + k) * 64 + t];
      P[2048 + t] = ptrs.p[24][t];   // cb1
      P[2112 + t] = ptrs.p[26][t];   // cb2
      for (int c = 0; c < 3; ++c)    // rWT[3][64]
        P[2308 + c * 64 + t] = ptrs.p[27][t * 3 + c];
    }
    if (t == 0) {
      P[2304] = ptrs.p[20][0];                 // sb
      P[2500] = ptrs.p[28][0];
      P[2501] = ptrs.p[28][1];
      P[2502] = ptrs.p[28][2];                 // rb
    }
    if (t < 3)  P[2305 + t] = 0.f;
    if (t < 57) P[2503 + t] = 0.f;
    return;
  }
  // 131072 f16 weight-fragment elements across blocks 1..512
  const int e = (blockIdx.x - 1) * 256 + t;
  float v; int dst;
  if (e < 114688) {                       // L1..L7 (128x128, 32 frags each)
    const int img = e >> 14, o = e & 16383;
    const int j = o & 7, lane = (o >> 3) & 63, m = (o >> 9) & 7, T = o >> 12;
    const int kraw = m * 16 + ((lane >> 5) << 3) + j;
    const int k = (img == 0) ? kraw : klog32(kraw);
    const int och = T * 32 + (lane & 31);
    v = ptrs.p[5 + 2 * img][(k + (img == 4 ? 67 : 0)) * 128 + och];
    dst = img * 32768 + (((T * 8 + m) * 64 + lane) << 4) + (j << 1);
  } else if (e < 122880) {                // C0h (64x128, 16 frags)
    const int o = e - 114688;
    const int j = o & 7, lane = (o >> 3) & 63, m = (o >> 9) & 7, T = o >> 12;
    const int k = klog32(m * 16 + ((lane >> 5) << 3) + j);
    const int och = T * 32 + (lane & 31);
    v = ptrs.p[21][k * 64 + och];
    dst = 229376 + (((T * 8 + m) * 64 + lane) << 4) + (j << 1);
  } else if (e < 126976) {                // C1 (64x64, 8 frags)
    const int o = e - 122880;
    const int j = o & 7, lane = (o >> 3) & 63, m = (o >> 9) & 3, T = o >> 11;
    const int k = klog32(m * 16 + ((lane >> 5) << 3) + j);
    const int och = T * 32 + (lane & 31);
    v = ptrs.p[23][k * 64 + och];
    dst = 245760 + (((T * 4 + m) * 64 + lane) << 4) + (j << 1);
  } else {                                // C2 (64x64, 8 frags)
    const int o = e - 126976;
    const int j = o & 7, lane = (o >> 3) & 63, m = (o >> 9) & 3, T = o >> 11;
    const int k = klog32(m * 16 + ((lane >> 5) << 3) + j);
    const int och = T * 32 + (lane & 31);
    v = ptrs.p[25][k * 64 + och];
    dst = 253952 + (((T * 4 + m) * 64 + lane) << 4) + (j << 1);
  }
  *(f16*)(ws + dst) = (f16)v;
}

// ---------------------------------------------------------------------------
// helpers
// ---------------------------------------------------------------------------
__device__ __forceinline__ void loadF4(f16x8* A, const char* __restrict__ img,
                                       int fb, int lane) {
#pragma unroll
  for (int i = 0; i < 4; ++i)
    A[i] = *(const f16x8*)(img + (((fb + i) * 64 + lane) << 4));
}

// pack two f32x4 -> f16x8 via cvt_pkrtz, then packed relu
__device__ __forceinline__ f16x8 packRelu(const f32x4 v0, const f32x4 v1) {
  const hf16x2 p0 = __builtin_amdgcn_cvt_pkrtz(v0[0], v0[1]);
  const hf16x2 p1 = __builtin_amdgcn_cvt_pkrtz(v0[2], v0[3]);
  const hf16x2 p2 = __builtin_amdgcn_cvt_pkrtz(v1[0], v1[1]);
  const hf16x2 p3 = __builtin_amdgcn_cvt_pkrtz(v1[2], v1[3]);
  f16x8 hb;
  hb[0] = (f16)p0[0]; hb[1] = (f16)p0[1]; hb[2] = (f16)p1[0]; hb[3] = (f16)p1[1];
  hb[4] = (f16)p2[0]; hb[5] = (f16)p2[1]; hb[6] = (f16)p3[0]; hb[7] = (f16)p3[1];
#pragma unroll
  for (int e2 = 0; e2 < 8; ++e2)
    hb[e2] = hb[e2] > (f16)0.f ? hb[e2] : (f16)0.f;
  return hb;
}

// ---------------------------------------------------------------------------
// Chunk with SINGLE-TILE acc (acc1[2] = 32 regs): och-tile at runtime offset
// ob = T*32, k-half KH. KH==0 seeds via the MFMA C operand.
// ---------------------------------------------------------------------------
template<int KH, int INIT>
__device__ __forceinline__ void qL32s(const f16x8 B[2][8], f32x16 acc1[2],
                                      const f16x8* A, const float* __restrict__ P,
                                      const float px[2][3],
                                      const float* __restrict__ vw2,
                                      int biasOff, int ob, int h4, int wbase) {
  if (KH == 0) {
    f32x4 bq[4];
#pragma unroll
    for (int q = 0; q < 4; ++q)
      bq[q] = *(const f32x4*)(P + biasOff + ob + q * 8 + h4);
    f32x4 e0[4], e1[4], e2[4];
    if (INIT == 1) {
#pragma unroll
      for (int q = 0; q < 4; ++q) {
        e0[q] = *(const f32x4*)(P + 640 + ob + q * 8 + h4);
        e1[q] = *(const f32x4*)(P + 768 + ob + q * 8 + h4);
        e2[q] = *(const f32x4*)(P + 896 + ob + q * 8 + h4);
      }
    } else if (INIT == 2) {
#pragma unroll
      for (int q = 0; q < 4; ++q) {
        e0[q] = *(const f32x4*)(P + 1856 + ob + q * 8 + h4);
        e1[q] = *(const f32x4*)(P + 1920 + ob + q * 8 + h4);
        e2[q] = *(const f32x4*)(P + 1984 + ob + q * 8 + h4);
      }
    }
    __builtin_amdgcn_s_setprio(1);
#pragma unroll
    for (int pt = 0; pt < 2; ++pt) {
      f32x16 s;
#pragma unroll
      for (int q = 0; q < 4; ++q) {
        f32x4 vq = bq[q];
        if (INIT == 1)
          vq += px[pt][0] * e0[q] + px[pt][1] * e1[q] + px[pt][2] * e2[q];
        if (INIT == 2) {
          const int ray = (wbase + pt * 32) >> 7;   // wave-uniform
          vq += vw2[ray * 3] * e0[q] + vw2[ray * 3 + 1] * e1[q]
              + vw2[ray * 3 + 2] * e2[q];
        }
#pragma unroll
        for (int e3 = 0; e3 < 4; ++e3) s[q * 4 + e3] = vq[e3];
      }
      acc1[pt] = __builtin_amdgcn_mfma_f32_32x32x16_f16(A[0], B[pt][KH * 4 + 0],
                                                        s, 0, 0, 0);
    }
#pragma unroll
    for (int i = 1; i < 4; ++i)
#pragma unroll
      for (int pt = 0; pt < 2; ++pt)
        acc1[pt] = __builtin_amdgcn_mfma_f32_32x32x16_f16(
            A[i], B[pt][KH * 4 + i], acc1[pt], 0, 0, 0);
    __builtin_amdgcn_s_setprio(0);
  } else {
    __builtin_amdgcn_s_setprio(1);
#pragma unroll
    for (int i = 0; i < 4; ++i)
#pragma unroll
      for (int pt = 0; pt < 2; ++pt)
        acc1[pt] = __builtin_amdgcn_mfma_f32_32x32x16_f16(
            A[i], B[pt][KH * 4 + i], acc1[pt], 0, 0, 0);
    __builtin_amdgcn_s_setprio(0);
  }
}

// single-tile convert: acc1 -> B[pt][2T], [2T+1]
template<int T>
__device__ __forceinline__ void toBtileS(const f32x16 acc1[2], f16x8 B[2][8]) {
#pragma unroll
  for (int pt = 0; pt < 2; ++pt) {
    f32x4 v0, v1, v2, v3;
#pragma unroll
    for (int e3 = 0; e3 < 4; ++e3) {
      v0[e3] = acc1[pt][e3];
      v1[e3] = acc1[pt][4 + e3];
      v2[e3] = acc1[pt][8 + e3];
      v3[e3] = acc1[pt][12 + e3];
    }
    B[pt][2 * T]     = packRelu(v0, v1);
    B[pt][2 * T + 1] = packRelu(v2, v3);
  }
}

// fused sigma partial for L7 tile T
template<int T>
__device__ __forceinline__ void sigTile(const f32x16 acc1[2], float sig[2],
                                        const float* __restrict__ P, int h4) {
#pragma unroll
  for (int pt = 0; pt < 2; ++pt) {
    float s = sig[pt];
#pragma unroll
    for (int q = 0; q < 4; ++q) {
      const f32x4 wq = *(const f32x4*)(P + 2176 + T * 32 + q * 8 + h4);
#pragma unroll
      for (int e3 = 0; e3 < 4; ++e3)
        s += fmaxf(acc1[pt][q * 4 + e3], 0.f) * wq[e3];
    }
    sig[pt] = s;
  }
}

// fused rgb partial for C2 tile T
template<int T>
__device__ __forceinline__ void rgbTile(const f32x16 acc1[2], float r0[2],
                                        float r1[2], float r2[2],
                                        const float* __restrict__ P, int h4) {
#pragma unroll
  for (int pt = 0; pt < 2; ++pt) {
    float a0 = r0[pt], a1 = r1[pt], a2 = r2[pt];
#pragma unroll
    for (int q = 0; q < 4; ++q) {
      const int ob = T * 32 + q * 8 + h4;
      const f32x4 w0 = *(const f32x4*)(P + 2308 + ob);
      const f32x4 w1 = *(const f32x4*)(P + 2372 + ob);
      const f32x4 w2 = *(const f32x4*)(P + 2436 + ob);
#pragma unroll
      for (int e3 = 0; e3 < 4; ++e3) {
        const float h = fmaxf(acc1[pt][q * 4 + e3], 0.f);
        a0 += h * w0[e3]; a1 += h * w1[e3]; a2 += h * w2[e3];
      }
    }
    r0[pt] = a0; r1[pt] = a1; r2[pt] = a2;
  }
}

// ---------------------------------------------------------------------------
// Main: 512 threads, __launch_bounds__(512,2), grid 512 — blessed config.
// 512 pts/block, 8 waves x 64 pts, 32x32x16 MFMA, zero act-LDS, one barrier.
// Single-tile acc (32 AGPR) + 4-buffer A rotation (3 chunks in flight).
// ---------------------------------------------------------------------------
__global__ __launch_bounds__(512, 2) void nerf_main(
    const float* __restrict__ pos, const float* __restrict__ view,
    const char* __restrict__ ws, float* __restrict__ out) {
  __shared__ __align__(16) float Lp[2560 + 1536 + 16];  // params | pos | view
  const int t = threadIdx.x, lane = t & 63, w = t >> 6;
  const int c32 = lane & 31;
  const int h4 = ((lane >> 5) << 2), h8 = ((lane >> 5) << 3);
  const int base = blockIdx.x * 512;   // 512 points per block
  const int wbase = w * 64;            // 64 points per wave
  const float* P = Lp;
  float* Lpos = Lp + 2560;
  float* Lvw = Lp + 4096;

  for (int i = t; i < 2560; i += 512) Lp[i] = ((const float*)(ws + WS_PARAMS))[i];
  for (int i = t; i < 1536; i += 512) Lpos[i] = pos[base * 3 + i];
  if (t < 12) Lvw[t] = view[(base >> 7) * 3 + t];
  __syncthreads();

  // 4-buffer A rotation; prologue holds L1 chunks 0..3 (T0K0,T0K1,T1K0,T1K1)
  f16x8 Aa0[4], Aa1[4], Aa2[4], Aa3[4];
  loadF4(Aa0, ws + 0, 0, lane);
  loadF4(Aa1, ws + 0, 4, lane);
  loadF4(Aa2, ws + 0, 8, lane);
  loadF4(Aa3, ws + 0, 12, lane);

  float px[2][3];
#pragma unroll
  for (int pt = 0; pt < 2; ++pt) {
    const int lp = wbase + pt * 32 + c32;
#pragma unroll
    for (int d = 0; d < 3; ++d) px[pt][d] = Lpos[lp * 3 + d];
  }

  // ---- L0: build L1's B-frags directly (natural k: ch = 16m + 8h + j) ----
  f16x8 Bx[2][8], By[2][8];
#pragma unroll
  for (int m = 0; m < 8; ++m) {
    const int chb = m * 16 + h8;
    const f32x4 b0  = *(const f32x4*)(P + chb),       b1  = *(const f32x4*)(P + chb + 4);
    const f32x4 w00 = *(const f32x4*)(P + 128 + chb), w01 = *(const f32x4*)(P + 128 + chb + 4);
    const f32x4 w10 = *(const f32x4*)(P + 256 + chb), w11 = *(const f32x4*)(P + 256 + chb + 4);
    const f32x4 w20 = *(const f32x4*)(P + 384 + chb), w21 = *(const f32x4*)(P + 384 + chb + 4);
#pragma unroll
    for (int pt = 0; pt < 2; ++pt) {
      const f32x4 v0 = b0 + px[pt][0] * w00 + px[pt][1] * w10 + px[pt][2] * w20;
      const f32x4 v1 = b1 + px[pt][0] * w01 + px[pt][1] * w11 + px[pt][2] * w21;
      Bx[pt][m] = packRelu(v0, v1);
    }
  }

  f32x16 acc1[2];
  float sig[2] = {0.f, 0.f};
  float r0[2] = {0.f, 0.f}, r1[2] = {0.f, 0.f}, r2[2] = {0.f, 0.f};

  // chunk: compute from buffer, then reload that buffer with chunk+4
#define DCH(Ab_, imgN, fbN, Bin, KH_, INIT_, ob_, bias_)                       \
  qL32s<KH_, INIT_>(Bin, acc1, Ab_, P, px, Lvw, bias_, ob_, h4, wbase);        \
  loadF4(Ab_, imgN, fbN, lane);
#define DCHN(Ab_, Bin, KH_, INIT_, ob_, bias_)                                 \
  qL32s<KH_, INIT_>(Bin, acc1, Ab_, P, px, Lvw, bias_, ob_, h4, wbase);

#define DLAYER(Bin, Bout, img_, imgNext, BIAS, INIT_)                          \
  DCH(Aa0, img_, 16, Bin, 0, INIT_,  0, BIAS)                                  \
  DCH(Aa1, img_, 20, Bin, 1, INIT_,  0, BIAS)                                  \
  toBtileS<0>(acc1, Bout);                                                     \
  DCH(Aa2, img_, 24, Bin, 0, INIT_, 32, BIAS)                                  \
  DCH(Aa3, img_, 28, Bin, 1, INIT_, 32, BIAS)                                  \
  toBtileS<1>(acc1, Bout);                                                     \
  DCH(Aa0, imgNext, 0, Bin, 0, INIT_, 64, BIAS)                                \
  DCH(Aa1, imgNext, 4, Bin, 1, INIT_, 64, BIAS)                                \
  toBtileS<2>(acc1, Bout);                                                     \
  DCH(Aa2, imgNext, 8, Bin, 0, INIT_, 96, BIAS)                                \
  DCH(Aa3, imgNext, 12, Bin, 1, INIT_, 96, BIAS)                               \
  toBtileS<3>(acc1, Bout);

  // L7: sigma partial fused per tile before the acc is recycled
#define DLAYER7(Bin, Bout, img_, imgNext, BIAS)                                \
  DCH(Aa0, img_, 16, Bin, 0, 0,  0, BIAS)                                      \
  DCH(Aa1, img_, 20, Bin, 1, 0,  0, BIAS)                                      \
  sigTile<0>(acc1, sig, P, h4); toBtileS<0>(acc1, Bout);                       \
  DCH(Aa2, img_, 24, Bin, 0, 0, 32, BIAS)                                      \
  DCH(Aa3, img_, 28, Bin, 1, 0, 32, BIAS)                                      \
  sigTile<1>(acc1, sig, P, h4); toBtileS<1>(acc1, Bout);                       \
  DCH(Aa0, imgNext, 0, Bin, 0, 0, 64, BIAS)                                    \
  DCH(Aa1, imgNext, 4, Bin, 1, 0, 64, BIAS)                                    \
  sigTile<2>(acc1, sig, P, h4); toBtileS<2>(acc1, Bout);                       \
  DCH(Aa2, imgNext, 8, Bin, 0, 0, 96, BIAS)                                    \
  DCH(Aa3, imgNext, 12, Bin, 1, 0, 96, BIAS)                                   \
  sigTile<3>(acc1, sig, P, h4); toBtileS<3>(acc1, Bout);

  DLAYER(Bx, By, ws +      0, ws +  32768, 1024, 0)   // L1
  DLAYER(By, Bx, ws +  32768, ws +  65536, 1152, 0)   // L2
  DLAYER(Bx, By, ws +  65536, ws +  98304, 1280, 0)   // L3
  DLAYER(By, Bx, ws +  98304, ws + 131072, 1408, 0)   // L4
  DLAYER(Bx, By, ws + 131072, ws + 163840,  512, 1)   // L5 (skip)
  DLAYER(By, Bx, ws + 163840, ws + 196608, 1536, 0)   // L6
  DLAYER7(Bx, By, ws + 196608, ws + 229376, 1664)     // L7 (preloads C0 c0..3)

  // finalize sigma (cross-half reduce)
#pragma unroll
  for (int pt = 0; pt < 2; ++pt) {
    float s = sig[pt];
    s += __shfl_xor(s, 32);
    sig[pt] = s + P[2304];
  }

  // ---- C0 (By -> Bx), 4 chunks; tail loads C1 c0,c1 / C2 c0,c1 ----
  DCH(Aa0, ws + 245760, 0, By, 0, 2,  0, 1792)
  DCH(Aa1, ws + 245760, 4, By, 1, 2,  0, 1792)
  toBtileS<0>(acc1, Bx);
  DCH(Aa2, ws + 253952, 0, By, 0, 2, 32, 1792)
  DCH(Aa3, ws + 253952, 4, By, 1, 2, 32, 1792)
  toBtileS<1>(acc1, Bx);

  // ---- C1 (Bx -> By), K=64: one chunk per tile, no further loads ----
  DCHN(Aa0, Bx, 0, 0,  0, 2048)
  toBtileS<0>(acc1, By);
  DCHN(Aa1, Bx, 0, 0, 32, 2048)
  toBtileS<1>(acc1, By);

  // ---- C2 (By), K=64: rgb fused per tile ----
  DCHN(Aa2, By, 0, 0,  0, 2112)
  rgbTile<0>(acc1, r0, r1, r2, P, h4);
  DCHN(Aa3, By, 0, 0, 32, 2112)
  rgbTile<1>(acc1, r0, r1, r2, P, h4);

#undef DCH
#undef DCHN
#undef DLAYER
#undef DLAYER7

  // ---- finalize rgb, store float4 ----
#pragma unroll
  for (int pt = 0; pt < 2; ++pt) {
    float a0 = r0[pt], a1 = r1[pt], a2 = r2[pt];
    a0 += __shfl_xor(a0, 32);
    a1 += __shfl_xor(a1, 32);
    a2 += __shfl_xor(a2, 32);
    if (lane < 32) {
      float4 o;
      o.x = a0 + P[2500]; o.y = a1 + P[2501]; o.z = a2 + P[2502]; o.w = sig[pt];
      *(float4*)(out + (base + wbase + pt * 32 + c32) * 4) = o;
    }
  }
}

extern "C" void kernel_launch(void* const* d_in, const int* in_sizes, int n_in,
                              void* d_out, int out_size, void* d_ws, size_t ws_size,
                              hipStream_t stream) {
  Ptrs ptrs;
  for (int i = 0; i < 29; ++i) ptrs.p[i] = (const float*)d_in[i];
  char* ws = (char*)d_ws;
  nerf_prep<<<513, 256, 0, stream>>>(ptrs, ws);
  nerf_main<<<512, 512, 0, stream>>>((const float*)d_in[0], (const float*)d_in[2],
                                     ws, (float*)d_out);
}

// Round 20
// 77.853 us; speedup vs baseline: 1.5194x; 1.5194x over previous
//
#include <hip/hip_runtime.h>

typedef _Float16 f16;
typedef _Float16 f16x8 __attribute__((ext_vector_type(8)));
typedef float f32x4 __attribute__((ext_vector_type(4)));

// ---------------- d_ws layout ----------------
// [0, 262144) : f16 weight images, per-lane MFMA A-fragment order.
//   frag f = T*nks + ks at imgbase + (f*64 + lane)*16 + j*2, holding
//   W[k_logical][ch = T*16 + (lane&15)], k_raw = ks*32 + (lane>>4)*8 + j
//     k_logical = k_raw       for L1 (input from L0, raw order)
//     k_logical = klog(k_raw) for L2..L7, C0, C1, C2 (in-register chaining):
//     klog(q) = 32*(q>>5) + 16*((q>>2)&1) + 4*((q>>3)&3) + (q&3)
//   L1..L7 (128x128, nks=4): i*32768, i=0..6  (L5 uses dW5 rows 67+k)
//   C0h (128x64, nks=4): 229376 | C1 (64x64, nks=2): 245760 | C2: 253952
// [262144, +10240) : fp32 params block (same as R11..R15):
//   0 b0f[128] | 128 W0p[3][128] | 512 b5f[128] | 640 W5p[3][128]
//   1024 db1 1152 db2 1280 db3 1408 db4 1536 db6 1664 db7 (x128)
//   1792 cb0[64] | 1856 cWv[3][64] | 2048 cb1[64] | 2112 cb2[64]
//   2176 sW[128] | 2304 sb | 2308 rWT[3][64] | 2500 rb[3]
#define WS_PARAMS 262144

struct Ptrs { const float* p[29]; };

__device__ __forceinline__ int klogf(int q) {
  return ((q >> 5) << 5) | (((q >> 2) & 1) << 4) | (((q >> 3) & 3) << 2) | (q & 3);
}

// ---------------------------------------------------------------------------
// Prepass (verbatim from passing R11..R15)
// ---------------------------------------------------------------------------
__global__ void nerf_prep(Ptrs ptrs, char* __restrict__ ws) {
  const int t = threadIdx.x;
  if (blockIdx.x == 0) {
    float* P = (float*)(ws + WS_PARAMS);
    const float* cond = ptrs.p[1];
    const float* dW0 = ptrs.p[3];  const float* db0 = ptrs.p[4];
    const float* dW5 = ptrs.p[13]; const float* db5 = ptrs.p[14];
    if (t < 128) {
      float a0 = db0[t], a5 = db5[t];
      for (int k = 0; k < 64; ++k) {
        const float c = cond[k];
        a0 += c * dW0[(3 + k) * 128 + t];
        a5 += c * dW5[(3 + k) * 128 + t];
      }
      P[t] = a0;          // b0f
      P[512 + t] = a5;    // b5f
      for (int k = 0; k < 3; ++k) {
        P[128 + k * 128 + t] = dW0[k * 128 + t];   // W0p
        P[640 + k * 128 + t] = dW5[k * 128 + t];   // W5p
      }
      P[1024 + t] = ptrs.p[6][t];    // db1
      P[1152 + t] = ptrs.p[8][t];    // db2
      P[1280 + t] = ptrs.p[10][t];   // db3
      P[1408 + t] = ptrs.p[12][t];   // db4
      P[1536 + t] = ptrs.p[16][t];   // db6
      P[1664 + t] = ptrs.p[18][t];   // db7
      P[2176 + t] = ptrs.p[19][t];   // sW
    }
    if (t < 64) {
      P[1792 + t] = ptrs.p[22][t];   // cb0
      for (int k = 0; k < 3; ++k)    // cWv = cW0 rows 128..130
        P[1856 + k * 64 + t] = ptrs.p[21][(128 + k) * 64 + t];
      P[2048 + t] = ptrs.p[24][t];   // cb1
      P[2112 + t] = ptrs.p[26][t];   // cb2
      for (int c = 0; c < 3; ++c)    // rWT[3][64]
        P[2308 + c * 64 + t] = ptrs.p[27][t * 3 + c];
    }
    if (t == 0) {
      P[2304] = ptrs.p[20][0];                 // sb
      P[2500] = ptrs.p[28][0];
      P[2501] = ptrs.p[28][1];
      P[2502] = ptrs.p[28][2];                 // rb
    }
    if (t < 3)  P[2305 + t] = 0.f;
    if (t < 57) P[2503 + t] = 0.f;
    return;
  }
  // 131072 f16 weight-fragment elements across blocks 1..512
  const int e = (blockIdx.x - 1) * 256 + t;
  float v; int dst;
  if (e < 114688) {                       // L1..L7
    const int img = e >> 14, o = e & 16383;
    const int j = o & 7, lane = (o >> 3) & 63, ks = (o >> 9) & 3, T = o >> 11;
    const int kraw = ks * 32 + ((lane >> 4) << 3) + j;
    const int k = (img == 0) ? kraw : klogf(kraw);
    const int ch = T * 16 + (lane & 15);
    v = ptrs.p[5 + 2 * img][(k + (img == 4 ? 67 : 0)) * 128 + ch];
    dst = img * 32768 + (((T * 4 + ks) * 64 + lane) << 4) + (j << 1);
  } else if (e < 122880) {                // C0h (input from L7: shuffled)
    const int o = e - 114688;
    const int j = o & 7, lane = (o >> 3) & 63, ks = (o >> 9) & 3, T = o >> 11;
    const int k = klogf(ks * 32 + ((lane >> 4) << 3) + j);
    const int ch = T * 16 + (lane & 15);
    v = ptrs.p[21][k * 64 + ch];
    dst = 229376 + (((T * 4 + ks) * 64 + lane) << 4) + (j << 1);
  } else if (e < 126976) {                // C1 (input from C0: shuffled)
    const int o = e - 122880;
    const int j = o & 7, lane = (o >> 3) & 63, ks = (o >> 9) & 1, T = o >> 10;
    const int k = klogf(ks * 32 + ((lane >> 4) << 3) + j);
    const int ch = T * 16 + (lane & 15);
    v = ptrs.p[23][k * 64 + ch];
    dst = 245760 + (((T * 2 + ks) * 64 + lane) << 4) + (j << 1);
  } else {                                // C2 (input from C1: shuffled)
    const int o = e - 126976;
    const int j = o & 7, lane = (o >> 3) & 63, ks = (o >> 9) & 1, T = o >> 10;
    const int k = klogf(ks * 32 + ((lane >> 4) << 3) + j);
    const int ch = T * 16 + (lane & 15);
    v = ptrs.p[25][k * 64 + ch];
    dst = 253952 + (((T * 2 + ks) * 64 + lane) << 4) + (j << 1);
  }
  *(f16*)(ws + dst) = (f16)v;
}

// ---------------------------------------------------------------------------
// 4-fragment burst load (one och-tile worth at NKS=4; two at NKS=2)
// ---------------------------------------------------------------------------
__device__ __forceinline__ void loadF4(f16x8* A, const char* __restrict__ img,
                                       int fragBase, int lane) {
#pragma unroll
  for (int i = 0; i < 4; ++i)
    A[i] = *(const f16x8*)(img + (((fragBase + i) * 64 + lane) << 4));
}

// ---------------------------------------------------------------------------
// Chunk: MFMAs for ct in [CTBASE, CTBASE+HCT), ptc = 4 point-tiles.
// INIT==0: bias enters as the C operand of the first-ks MFMA (no acc-init
// VALU at all — bit-identical to seed-then-accumulate).
// INIT==1/2: explicit seed (bias + pos*W5p / + view*cWv), as before.
// ---------------------------------------------------------------------------
template<int HCT, int NKS, int INIT, int CTBASE>
__device__ __forceinline__ void qL(const f16x8 B[4][4], f32x4 acc[4][8],
                                   const f16x8* A,
                                   const float* __restrict__ P,
                                   const float px[4][3],
                                   const float* __restrict__ vw2,
                                   int biasOff, int kg, int wbase) {
#pragma unroll
  for (int ct = 0; ct < HCT; ++ct) {
    const int ochB = (CTBASE + ct) * 16 + kg * 4;
    const f32x4 bq = *(const f32x4*)(P + biasOff + ochB);
    if (INIT == 0) {
      __builtin_amdgcn_s_setprio(1);
#pragma unroll
      for (int ptc = 0; ptc < 4; ++ptc)
        acc[ptc][CTBASE + ct] = __builtin_amdgcn_mfma_f32_16x16x32_f16(
            A[ct * NKS + 0], B[ptc][0], bq, 0, 0, 0);
#pragma unroll
      for (int ks = 1; ks < NKS; ++ks)
#pragma unroll
        for (int ptc = 0; ptc < 4; ++ptc)
          acc[ptc][CTBASE + ct] = __builtin_amdgcn_mfma_f32_16x16x32_f16(
              A[ct * NKS + ks], B[ptc][ks], acc[ptc][CTBASE + ct], 0, 0, 0);
      __builtin_amdgcn_s_setprio(0);
    } else {
      f32x4 e0, e1, e2;
      if (INIT == 1) {
        e0 = *(const f32x4*)(P + 640 + ochB);
        e1 = *(const f32x4*)(P + 768 + ochB);
        e2 = *(const f32x4*)(P + 896 + ochB);
      } else {
        e0 = *(const f32x4*)(P + 1856 + ochB);
        e1 = *(const f32x4*)(P + 1920 + ochB);
        e2 = *(const f32x4*)(P + 1984 + ochB);
      }
#pragma unroll
      for (int ptc = 0; ptc < 4; ++ptc) {
        f32x4 v = bq;
        if (INIT == 1)
          v += px[ptc][0] * e0 + px[ptc][1] * e1 + px[ptc][2] * e2;
        if (INIT == 2) {
          const int ray = (wbase + ptc * 16) >> 7;   // wave-uniform
          v += vw2[ray * 3] * e0 + vw2[ray * 3 + 1] * e1 + vw2[ray * 3 + 2] * e2;
        }
        acc[ptc][CTBASE + ct] = v;
      }
      __builtin_amdgcn_s_setprio(1);
#pragma unroll
      for (int ks = 0; ks < NKS; ++ks)
#pragma unroll
        for (int ptc = 0; ptc < 4; ++ptc)
          acc[ptc][CTBASE + ct] = __builtin_amdgcn_mfma_f32_16x16x32_f16(
              A[ct * NKS + ks], B[ptc][ks], acc[ptc][CTBASE + ct], 0, 0, 0);
      __builtin_amdgcn_s_setprio(0);
    }
  }
}

// relu+convert acc -> next layer's B. Convert (RNE) first, relu in f16
// (bit-identical to f32-relu-then-convert; enables v_pk_max_f16).
template<int NCT>
__device__ __forceinline__ void toB(const f32x4 acc[4][8], f16x8 B[4][4]) {
#pragma unroll
  for (int ptc = 0; ptc < 4; ++ptc)
#pragma unroll
    for (int ks = 0; ks < NCT / 2; ++ks) {
      f16x8 hb;
#pragma unroll
      for (int r = 0; r < 4; ++r) {
        hb[r]     = (f16)acc[ptc][2 * ks][r];
        hb[4 + r] = (f16)acc[ptc][2 * ks + 1][r];
      }
#pragma unroll
      for (int e = 0; e < 8; ++e)
        hb[e] = hb[e] > (f16)0.f ? hb[e] : (f16)0.f;
      B[ptc][ks] = hb;
    }
}

// ---------------------------------------------------------------------------
// Main: 512 threads, __launch_bounds__(512,2), grid 512 — as passing R14/R15.
// 512 pts/block, 8 waves x 64 pts (ptc=4), full 128-och/wave, zero act-LDS,
// one barrier. Chunk ping-pong Aa/Ab: load chunk(i+1) under MFMA chunk(i).
// ---------------------------------------------------------------------------
__global__ __launch_bounds__(512, 2) void nerf_main(
    const float* __restrict__ pos, const float* __restrict__ view,
    const char* __restrict__ ws, float* __restrict__ out) {
  __shared__ __align__(16) float Lp[2560 + 1536 + 16];  // params | pos | view
  const int t = threadIdx.x, lane = t & 63, w = t >> 6;
  const int c = lane & 15, kg = lane >> 4;
  const int base = blockIdx.x * 512;   // 512 points per block
  const int wbase = w * 64;            // 64 points per wave
  const float* P = Lp;
  float* Lpos = Lp + 2560;
  float* Lvw = Lp + 4096;

  for (int i = t; i < 2560; i += 512) Lp[i] = ((const float*)(ws + WS_PARAMS))[i];
  for (int i = t; i < 1536; i += 512) Lpos[i] = pos[base * 3 + i];
  if (t < 12) Lvw[t] = view[(base >> 7) * 3 + t];
  __syncthreads();

  f16x8 Aa[4], Ab[4];
  loadF4(Aa, ws + 0, 0, lane);         // L1 chunk0 — in flight during L0

  // per-lane pos for its four point-tiles
  float px[4][3];
#pragma unroll
  for (int ptc = 0; ptc < 4; ++ptc) {
    const int lp = wbase + ptc * 16 + c;
#pragma unroll
    for (int d = 0; d < 3; ++d) px[ptc][d] = Lpos[lp * 3 + d];
  }

  // ---- L0: emit h0 directly as L1's B-frags (raw k-order) ----
  f16x8 B[4][4];
#pragma unroll
  for (int ptc = 0; ptc < 4; ++ptc)
#pragma unroll
    for (int ks = 0; ks < 4; ++ks) {
      f16x8 hb;
#pragma unroll
      for (int j = 0; j < 8; ++j) {
        const int ch = ks * 32 + kg * 8 + j;
        const float v = P[ch] + px[ptc][0] * P[128 + ch] + px[ptc][1] * P[256 + ch]
                      + px[ptc][2] * P[384 + ch];
        hb[j] = (f16)fmaxf(v, 0.f);
      }
      B[ptc][ks] = hb;
    }

  f32x4 acc[4][8];

  // chunk q computes ct=q from buf (q even: Aa, q odd: Ab) and preloads the
  // next chunk into the other buf; chunk 7 preloads the NEXT layer's chunk 0.
#define QCE(CTB, img_, fb, BIAS, INIT_)                                        \
  loadF4(Ab, img_, fb, lane);                                                  \
  qL<1, 4, INIT_, CTB>(B, acc, Aa, P, px, Lvw, BIAS, kg, wbase);
#define QCO(CTB, img_, fb, BIAS, INIT_)                                        \
  loadF4(Aa, img_, fb, lane);                                                  \
  qL<1, 4, INIT_, CTB>(B, acc, Ab, P, px, Lvw, BIAS, kg, wbase);
#define DLAYER(img_, imgNext, BIAS, INIT_)                                     \
  QCE(0, img_,  4, BIAS, INIT_) QCO(1, img_,  8, BIAS, INIT_)                  \
  QCE(2, img_, 12, BIAS, INIT_) QCO(3, img_, 16, BIAS, INIT_)                  \
  QCE(4, img_, 20, BIAS, INIT_) QCO(5, img_, 24, BIAS, INIT_)                  \
  QCE(6, img_, 28, BIAS, INIT_) QCO(7, imgNext, 0, BIAS, INIT_)

  DLAYER(ws +      0, ws +  32768, 1024, 0) toB<8>(acc, B);  // L1
  DLAYER(ws +  32768, ws +  65536, 1152, 0) toB<8>(acc, B);  // L2
  DLAYER(ws +  65536, ws +  98304, 1280, 0) toB<8>(acc, B);  // L3
  DLAYER(ws +  98304, ws + 131072, 1408, 0) toB<8>(acc, B);  // L4
  DLAYER(ws + 131072, ws + 163840,  512, 1) toB<8>(acc, B);  // L5 (skip)
  DLAYER(ws + 163840, ws + 196608, 1536, 0) toB<8>(acc, B);  // L6
  DLAYER(ws + 196608, ws + 229376, 1664, 0)                  // L7 (preloads C0)
#undef DLAYER
#undef QCE
#undef QCO

  // ---- sigma from L7 acc (f32, relu'd), in-register reduce ----
  float sig[4];
#pragma unroll
  for (int ptc = 0; ptc < 4; ++ptc) {
    float s = 0.f;
#pragma unroll
    for (int ct = 0; ct < 8; ++ct) {
      const f32x4 wq = *(const f32x4*)(P + 2176 + ct * 16 + kg * 4);
      const f32x4 a = acc[ptc][ct];
#pragma unroll
      for (int r = 0; r < 4; ++r) s += fmaxf(a[r], 0.f) * wq[r];
    }
    s += __shfl_xor(s, 16);
    s += __shfl_xor(s, 32);
    sig[ptc] = s + P[2304];
  }
  toB<8>(acc, B);                                            // h7 -> C0 B

  // ---- color chain. C0: NCT=4, NKS=4 (chunk0 already in Aa) ----
  loadF4(Ab, ws + 229376,  4, lane);
  qL<1, 4, 2, 0>(B, acc, Aa, P, px, Lvw, 1792, kg, wbase);
  loadF4(Aa, ws + 229376,  8, lane);
  qL<1, 4, 2, 1>(B, acc, Ab, P, px, Lvw, 1792, kg, wbase);
  loadF4(Ab, ws + 229376, 12, lane);
  qL<1, 4, 2, 2>(B, acc, Aa, P, px, Lvw, 1792, kg, wbase);
  loadF4(Aa, ws + 245760,  0, lane);                         // C1 ct0-1
  qL<1, 4, 2, 3>(B, acc, Ab, P, px, Lvw, 1792, kg, wbase);
  toB<4>(acc, B);                                            // C0 -> B (ks 0-1)

  // C1: NCT=4, NKS=2 (chunk = 2 ct)
  loadF4(Ab, ws + 245760, 4, lane);                          // C1 ct2-3
  qL<2, 2, 0, 0>(B, acc, Aa, P, px, Lvw, 2048, kg, wbase);
  loadF4(Aa, ws + 253952, 0, lane);                          // C2 ct0-1
  qL<2, 2, 0, 2>(B, acc, Ab, P, px, Lvw, 2048, kg, wbase);
  toB<4>(acc, B);                                            // C1 -> B

  // C2
  loadF4(Ab, ws + 253952, 4, lane);                          // C2 ct2-3
  qL<2, 2, 0, 0>(B, acc, Aa, P, px, Lvw, 2112, kg, wbase);
  qL<2, 2, 0, 2>(B, acc, Ab, P, px, Lvw, 2112, kg, wbase);

  // ---- rgb from C2 acc, in-register reduce; lanes kg==0 store float4 ----
#pragma unroll
  for (int ptc = 0; ptc < 4; ++ptc) {
    float a0 = 0.f, a1 = 0.f, a2 = 0.f;
#pragma unroll
    for (int ct = 0; ct < 4; ++ct) {
      const int ochB = ct * 16 + kg * 4;
      const f32x4 r0 = *(const f32x4*)(P + 2308 + ochB);
      const f32x4 r1 = *(const f32x4*)(P + 2372 + ochB);
      const f32x4 r2 = *(const f32x4*)(P + 2436 + ochB);
      const f32x4 a = acc[ptc][ct];
#pragma unroll
      for (int r = 0; r < 4; ++r) {
        const float h = fmaxf(a[r], 0.f);
        a0 += h * r0[r]; a1 += h * r1[r]; a2 += h * r2[r];
      }
    }
    a0 += __shfl_xor(a0, 16); a0 += __shfl_xor(a0, 32);
    a1 += __shfl_xor(a1, 16); a1 += __shfl_xor(a1, 32);
    a2 += __shfl_xor(a2, 16); a2 += __shfl_xor(a2, 32);
    if (kg == 0) {
      float4 o;
      o.x = a0 + P[2500]; o.y = a1 + P[2501]; o.z = a2 + P[2502]; o.w = sig[ptc];
      *(float4*)(out + (base + wbase + ptc * 16 + c) * 4) = o;
    }
  }
}

extern "C" void kernel_launch(void* const* d_in, const int* in_sizes, int n_in,
                              void* d_out, int out_size, void* d_ws, size_t ws_size,
                              hipStream_t stream) {
  Ptrs ptrs;
  for (int i = 0; i < 29; ++i) ptrs.p[i] = (const float*)d_in[i];
  char* ws = (char*)d_ws;
  nerf_prep<<<513, 256, 0, stream>>>(ptrs, ws);
  nerf_main<<<512, 512, 0, stream>>>((const float*)d_in[0], (const float*)d_in[2],
                                     ws, (float*)d_out);
}

// Round 21
// 77.367 us; speedup vs baseline: 1.5289x; 1.0063x over previous
//
#include <hip/hip_runtime.h>

typedef _Float16 f16;
typedef _Float16 f16x8 __attribute__((ext_vector_type(8)));
typedef __fp16 hf16x2 __attribute__((ext_vector_type(2)));
typedef float f32x4 __attribute__((ext_vector_type(4)));

// ---------------- d_ws layout ----------------
// [0, 262144) : f16 weight images, per-lane MFMA A-fragment order.
//   frag f = T*nks + ks at imgbase + (f*64 + lane)*16 + j*2, holding
//   W[k_logical][ch = T*16 + (lane&15)], k_raw = ks*32 + (lane>>4)*8 + j
//     k_logical = k_raw       for L1 (input from L0, raw order)
//     k_logical = klog(k_raw) for L2..L7, C0, C1, C2 (in-register chaining):
//     klog(q) = 32*(q>>5) + 16*((q>>2)&1) + 4*((q>>3)&3) + (q&3)
//   L1..L7 (128x128, nks=4): i*32768, i=0..6  (L5 uses dW5 rows 67+k)
//   C0h (128x64, nks=4): 229376 | C1 (64x64, nks=2): 245760 | C2: 253952
// [262144, +10240) : fp32 params block (same as R11..R20):
//   0 b0f[128] | 128 W0p[3][128] | 512 b5f[128] | 640 W5p[3][128]
//   1024 db1 1152 db2 1280 db3 1408 db4 1536 db6 1664 db7 (x128)
//   1792 cb0[64] | 1856 cWv[3][64] | 2048 cb1[64] | 2112 cb2[64]
//   2176 sW[128] | 2304 sb | 2308 rWT[3][64] | 2500 rb[3]
#define WS_PARAMS 262144

struct Ptrs { const float* p[29]; };

__device__ __forceinline__ int klogf(int q) {
  return ((q >> 5) << 5) | (((q >> 2) & 1) << 4) | (((q >> 3) & 3) << 2) | (q & 3);
}

// ---------------------------------------------------------------------------
// Prepass (verbatim from passing R11..R20)
// ---------------------------------------------------------------------------
__global__ void nerf_prep(Ptrs ptrs, char* __restrict__ ws) {
  const int t = threadIdx.x;
  if (blockIdx.x == 0) {
    float* P = (float*)(ws + WS_PARAMS);
    const float* cond = ptrs.p[1];
    const float* dW0 = ptrs.p[3];  const float* db0 = ptrs.p[4];
    const float* dW5 = ptrs.p[13]; const float* db5 = ptrs.p[14];
    if (t < 128) {
      float a0 = db0[t], a5 = db5[t];
      for (int k = 0; k < 64; ++k) {
        const float c = cond[k];
        a0 += c * dW0[(3 + k) * 128 + t];
        a5 += c * dW5[(3 + k) * 128 + t];
      }
      P[t] = a0;          // b0f
      P[512 + t] = a5;    // b5f
      for (int k = 0; k < 3; ++k) {
        P[128 + k * 128 + t] = dW0[k * 128 + t];   // W0p
        P[640 + k * 128 + t] = dW5[k * 128 + t];   // W5p
      }
      P[1024 + t] = ptrs.p[6][t];    // db1
      P[1152 + t] = ptrs.p[8][t];    // db2
      P[1280 + t] = ptrs.p[10][t];   // db3
      P[1408 + t] = ptrs.p[12][t];   // db4
      P[1536 + t] = ptrs.p[16][t];   // db6
      P[1664 + t] = ptrs.p[18][t];   // db7
      P[2176 + t] = ptrs.p[19][t];   // sW
    }
    if (t < 64) {
      P[1792 + t] = ptrs.p[22][t];   // cb0
      for (int k = 0; k < 3; ++k)    // cWv = cW0 rows 128..130
        P[1856 + k * 64 + t] = ptrs.p[21][(128 + k) * 64 + t];
      P[2048 + t] = ptrs.p[24][t];   // cb1
      P[2112 + t] = ptrs.p[26][t];   // cb2
      for (int c = 0; c < 3; ++c)    // rWT[3][64]
        P[2308 + c * 64 + t] = ptrs.p[27][t * 3 + c];
    }
    if (t == 0) {
      P[2304] = ptrs.p[20][0];                 // sb
      P[2500] = ptrs.p[28][0];
      P[2501] = ptrs.p[28][1];
      P[2502] = ptrs.p[28][2];                 // rb
    }
    if (t < 3)  P[2305 + t] = 0.f;
    if (t < 57) P[2503 + t] = 0.f;
    return;
  }
  // 131072 f16 weight-fragment elements across blocks 1..512
  const int e = (blockIdx.x - 1) * 256 + t;
  float v; int dst;
  if (e < 114688) {                       // L1..L7
    const int img = e >> 14, o = e & 16383;
    const int j = o & 7, lane = (o >> 3) & 63, ks = (o >> 9) & 3, T = o >> 11;
    const int kraw = ks * 32 + ((lane >> 4) << 3) + j;
    const int k = (img == 0) ? kraw : klogf(kraw);
    const int ch = T * 16 + (lane & 15);
    v = ptrs.p[5 + 2 * img][(k + (img == 4 ? 67 : 0)) * 128 + ch];
    dst = img * 32768 + (((T * 4 + ks) * 64 + lane) << 4) + (j << 1);
  } else if (e < 122880) {                // C0h (input from L7: shuffled)
    const int o = e - 114688;
    const int j = o & 7, lane = (o >> 3) & 63, ks = (o >> 9) & 3, T = o >> 11;
    const int k = klogf(ks * 32 + ((lane >> 4) << 3) + j);
    const int ch = T * 16 + (lane & 15);
    v = ptrs.p[21][k * 64 + ch];
    dst = 229376 + (((T * 4 + ks) * 64 + lane) << 4) + (j << 1);
  } else if (e < 126976) {                // C1 (input from C0: shuffled)
    const int o = e - 122880;
    const int j = o & 7, lane = (o >> 3) & 63, ks = (o >> 9) & 1, T = o >> 10;
    const int k = klogf(ks * 32 + ((lane >> 4) << 3) + j);
    const int ch = T * 16 + (lane & 15);
    v = ptrs.p[23][k * 64 + ch];
    dst = 245760 + (((T * 2 + ks) * 64 + lane) << 4) + (j << 1);
  } else {                                // C2 (input from C1: shuffled)
    const int o = e - 126976;
    const int j = o & 7, lane = (o >> 3) & 63, ks = (o >> 9) & 1, T = o >> 10;
    const int k = klogf(ks * 32 + ((lane >> 4) << 3) + j);
    const int ch = T * 16 + (lane & 15);
    v = ptrs.p[25][k * 64 + ch];
    dst = 253952 + (((T * 2 + ks) * 64 + lane) << 4) + (j << 1);
  }
  *(f16*)(ws + dst) = (f16)v;
}

// ---------------------------------------------------------------------------
// 4-fragment burst load (one och-tile worth at NKS=4; two at NKS=2)
// ---------------------------------------------------------------------------
__device__ __forceinline__ void loadF4(f16x8* A, const char* __restrict__ img,
                                       int fragBase, int lane) {
#pragma unroll
  for (int i = 0; i < 4; ++i)
    A[i] = *(const f16x8*)(img + (((fragBase + i) * 64 + lane) << 4));
}

// pack two f32x4 -> f16x8 via cvt_pkrtz, then packed relu
// (hardware-validated in passing R17/R18; RTZ convert, end-to-end 4.9e-4)
__device__ __forceinline__ f16x8 packRelu(const f32x4 v0, const f32x4 v1) {
  const hf16x2 p0 = __builtin_amdgcn_cvt_pkrtz(v0[0], v0[1]);
  const hf16x2 p1 = __builtin_amdgcn_cvt_pkrtz(v0[2], v0[3]);
  const hf16x2 p2 = __builtin_amdgcn_cvt_pkrtz(v1[0], v1[1]);
  const hf16x2 p3 = __builtin_amdgcn_cvt_pkrtz(v1[2], v1[3]);
  f16x8 hb;
  hb[0] = (f16)p0[0]; hb[1] = (f16)p0[1]; hb[2] = (f16)p1[0]; hb[3] = (f16)p1[1];
  hb[4] = (f16)p2[0]; hb[5] = (f16)p2[1]; hb[6] = (f16)p3[0]; hb[7] = (f16)p3[1];
#pragma unroll
  for (int e2 = 0; e2 < 8; ++e2)
    hb[e2] = hb[e2] > (f16)0.f ? hb[e2] : (f16)0.f;
  return hb;
}

// ---------------------------------------------------------------------------
// Chunk: MFMAs for ct in [CTBASE, CTBASE+HCT), ptc = 4 point-tiles.
// INIT==0: bias enters as the C operand of the first-ks MFMA.
// INIT==1/2: explicit seed (bias + pos*W5p / + view*cWv).
// ---------------------------------------------------------------------------
template<int HCT, int NKS, int INIT, int CTBASE>
__device__ __forceinline__ void qL(const f16x8 B[4][4], f32x4 acc[4][8],
                                   const f16x8* A,
                                   const float* __restrict__ P,
                                   const float px[4][3],
                                   const float* __restrict__ vw2,
                                   int biasOff, int kg, int wbase) {
#pragma unroll
  for (int ct = 0; ct < HCT; ++ct) {
    const int ochB = (CTBASE + ct) * 16 + kg * 4;
    const f32x4 bq = *(const f32x4*)(P + biasOff + ochB);
    if (INIT == 0) {
      __builtin_amdgcn_s_setprio(1);
#pragma unroll
      for (int ptc = 0; ptc < 4; ++ptc)
        acc[ptc][CTBASE + ct] = __builtin_amdgcn_mfma_f32_16x16x32_f16(
            A[ct * NKS + 0], B[ptc][0], bq, 0, 0, 0);
#pragma unroll
      for (int ks = 1; ks < NKS; ++ks)
#pragma unroll
        for (int ptc = 0; ptc < 4; ++ptc)
          acc[ptc][CTBASE + ct] = __builtin_amdgcn_mfma_f32_16x16x32_f16(
              A[ct * NKS + ks], B[ptc][ks], acc[ptc][CTBASE + ct], 0, 0, 0);
      __builtin_amdgcn_s_setprio(0);
    } else {
      f32x4 e0, e1, e2;
      if (INIT == 1) {
        e0 = *(const f32x4*)(P + 640 + ochB);
        e1 = *(const f32x4*)(P + 768 + ochB);
        e2 = *(const f32x4*)(P + 896 + ochB);
      } else {
        e0 = *(const f32x4*)(P + 1856 + ochB);
        e1 = *(const f32x4*)(P + 1920 + ochB);
        e2 = *(const f32x4*)(P + 1984 + ochB);
      }
#pragma unroll
      for (int ptc = 0; ptc < 4; ++ptc) {
        f32x4 v = bq;
        if (INIT == 1)
          v += px[ptc][0] * e0 + px[ptc][1] * e1 + px[ptc][2] * e2;
        if (INIT == 2) {
          const int ray = (wbase + ptc * 16) >> 7;   // wave-uniform
          v += vw2[ray * 3] * e0 + vw2[ray * 3 + 1] * e1 + vw2[ray * 3 + 2] * e2;
        }
        acc[ptc][CTBASE + ct] = v;
      }
      __builtin_amdgcn_s_setprio(1);
#pragma unroll
      for (int ks = 0; ks < NKS; ++ks)
#pragma unroll
        for (int ptc = 0; ptc < 4; ++ptc)
          acc[ptc][CTBASE + ct] = __builtin_amdgcn_mfma_f32_16x16x32_f16(
              A[ct * NKS + ks], B[ptc][ks], acc[ptc][CTBASE + ct], 0, 0, 0);
      __builtin_amdgcn_s_setprio(0);
    }
  }
}

// relu+convert acc -> next layer's B via packRelu (cvt_pkrtz: halves toB VALU)
template<int NCT>
__device__ __forceinline__ void toB(const f32x4 acc[4][8], f16x8 B[4][4]) {
#pragma unroll
  for (int ptc = 0; ptc < 4; ++ptc)
#pragma unroll
    for (int ks = 0; ks < NCT / 2; ++ks)
      B[ptc][ks] = packRelu(acc[ptc][2 * ks], acc[ptc][2 * ks + 1]);
}

// ---------------------------------------------------------------------------
// Main: 512 threads, __launch_bounds__(512,2), grid 512 — as passing R20.
// 512 pts/block, 8 waves x 64 pts (ptc=4), full 128-och/wave, zero act-LDS,
// one barrier. Chunk ping-pong Aa/Ab: load chunk(i+1) under MFMA chunk(i).
// ---------------------------------------------------------------------------
__global__ __launch_bounds__(512, 2) void nerf_main(
    const float* __restrict__ pos, const float* __restrict__ view,
    const char* __restrict__ ws, float* __restrict__ out) {
  __shared__ __align__(16) float Lp[2560 + 1536 + 16];  // params | pos | view
  const int t = threadIdx.x, lane = t & 63, w = t >> 6;
  const int c = lane & 15, kg = lane >> 4;
  const int base = blockIdx.x * 512;   // 512 points per block
  const int wbase = w * 64;            // 64 points per wave
  const float* P = Lp;
  float* Lpos = Lp + 2560;
  float* Lvw = Lp + 4096;

  for (int i = t; i < 2560; i += 512) Lp[i] = ((const float*)(ws + WS_PARAMS))[i];
  for (int i = t; i < 1536; i += 512) Lpos[i] = pos[base * 3 + i];
  if (t < 12) Lvw[t] = view[(base >> 7) * 3 + t];
  __syncthreads();

  f16x8 Aa[4], Ab[4];
  loadF4(Aa, ws + 0, 0, lane);         // L1 chunk0 — in flight during L0

  // per-lane pos for its four point-tiles
  float px[4][3];
#pragma unroll
  for (int ptc = 0; ptc < 4; ++ptc) {
    const int lp = wbase + ptc * 16 + c;
#pragma unroll
    for (int d = 0; d < 3; ++d) px[ptc][d] = Lpos[lp * 3 + d];
  }

  // ---- L0: emit h0 directly as L1's B-frags (raw k-order) ----
  f16x8 B[4][4];
#pragma unroll
  for (int ptc = 0; ptc < 4; ++ptc)
#pragma unroll
    for (int ks = 0; ks < 4; ++ks) {
      f16x8 hb;
#pragma unroll
      for (int j = 0; j < 8; ++j) {
        const int ch = ks * 32 + kg * 8 + j;
        const float v = P[ch] + px[ptc][0] * P[128 + ch] + px[ptc][1] * P[256 + ch]
                      + px[ptc][2] * P[384 + ch];
        hb[j] = (f16)fmaxf(v, 0.f);
      }
      B[ptc][ks] = hb;
    }

  f32x4 acc[4][8];

  // chunk q computes ct=q from buf (q even: Aa, q odd: Ab) and preloads the
  // next chunk into the other buf; chunk 7 preloads the NEXT layer's chunk 0.
#define QCE(CTB, img_, fb, BIAS, INIT_)                                        \
  loadF4(Ab, img_, fb, lane);                                                  \
  qL<1, 4, INIT_, CTB>(B, acc, Aa, P, px, Lvw, BIAS, kg, wbase);
#define QCO(CTB, img_, fb, BIAS, INIT_)                                        \
  loadF4(Aa, img_, fb, lane);                                                  \
  qL<1, 4, INIT_, CTB>(B, acc, Ab, P, px, Lvw, BIAS, kg, wbase);
#define DLAYER(img_, imgNext, BIAS, INIT_)                                     \
  QCE(0, img_,  4, BIAS, INIT_) QCO(1, img_,  8, BIAS, INIT_)                  \
  QCE(2, img_, 12, BIAS, INIT_) QCO(3, img_, 16, BIAS, INIT_)                  \
  QCE(4, img_, 20, BIAS, INIT_) QCO(5, img_, 24, BIAS, INIT_)                  \
  QCE(6, img_, 28, BIAS, INIT_) QCO(7, imgNext, 0, BIAS, INIT_)

  DLAYER(ws +      0, ws +  32768, 1024, 0) toB<8>(acc, B);  // L1
  DLAYER(ws +  32768, ws +  65536, 1152, 0) toB<8>(acc, B);  // L2
  DLAYER(ws +  65536, ws +  98304, 1280, 0) toB<8>(acc, B);  // L3
  DLAYER(ws +  98304, ws + 131072, 1408, 0) toB<8>(acc, B);  // L4
  DLAYER(ws + 131072, ws + 163840,  512, 1) toB<8>(acc, B);  // L5 (skip)
  DLAYER(ws + 163840, ws + 196608, 1536, 0) toB<8>(acc, B);  // L6
  DLAYER(ws + 196608, ws + 229376, 1664, 0)                  // L7 (preloads C0)
#undef DLAYER
#undef QCE
#undef QCO

  // ---- sigma from L7 acc (f32, relu'd), in-register reduce ----
  float sig[4];
#pragma unroll
  for (int ptc = 0; ptc < 4; ++ptc) {
    float s = 0.f;
#pragma unroll
    for (int ct = 0; ct < 8; ++ct) {
      const f32x4 wq = *(const f32x4*)(P + 2176 + ct * 16 + kg * 4);
      const f32x4 a = acc[ptc][ct];
#pragma unroll
      for (int r = 0; r < 4; ++r) s += fmaxf(a[r], 0.f) * wq[r];
    }
    s += __shfl_xor(s, 16);
    s += __shfl_xor(s, 32);
    sig[ptc] = s + P[2304];
  }
  toB<8>(acc, B);                                            // h7 -> C0 B

  // ---- color chain. C0: NCT=4, NKS=4 (chunk0 already in Aa) ----
  loadF4(Ab, ws + 229376,  4, lane);
  qL<1, 4, 2, 0>(B, acc, Aa, P, px, Lvw, 1792, kg, wbase);
  loadF4(Aa, ws + 229376,  8, lane);
  qL<1, 4, 2, 1>(B, acc, Ab, P, px, Lvw, 1792, kg, wbase);
  loadF4(Ab, ws + 229376, 12, lane);
  qL<1, 4, 2, 2>(B, acc, Aa, P, px, Lvw, 1792, kg, wbase);
  loadF4(Aa, ws + 245760,  0, lane);                         // C1 ct0-1
  qL<1, 4, 2, 3>(B, acc, Ab, P, px, Lvw, 1792, kg, wbase);
  toB<4>(acc, B);                                            // C0 -> B (ks 0-1)

  // C1: NCT=4, NKS=2 (chunk = 2 ct)
  loadF4(Ab, ws + 245760, 4, lane);                          // C1 ct2-3
  qL<2, 2, 0, 0>(B, acc, Aa, P, px, Lvw, 2048, kg, wbase);
  loadF4(Aa, ws + 253952, 0, lane);                          // C2 ct0-1
  qL<2, 2, 0, 2>(B, acc, Ab, P, px, Lvw, 2048, kg, wbase);
  toB<4>(acc, B);                                            // C1 -> B

  // C2
  loadF4(Ab, ws + 253952, 4, lane);                          // C2 ct2-3
  qL<2, 2, 0, 0>(B, acc, Aa, P, px, Lvw, 2112, kg, wbase);
  qL<2, 2, 0, 2>(B, acc, Ab, P, px, Lvw, 2112, kg, wbase);

  // ---- rgb from C2 acc, in-register reduce; lanes kg==0 store float4 ----
#pragma unroll
  for (int ptc = 0; ptc < 4; ++ptc) {
    float a0 = 0.f, a1 = 0.f, a2 = 0.f;
#pragma unroll
    for (int ct = 0; ct < 4; ++ct) {
      const int ochB = ct * 16 + kg * 4;
      const f32x4 r0 = *(const f32x4*)(P + 2308 + ochB);
      const f32x4 r1 = *(const f32x4*)(P + 2372 + ochB);
      const f32x4 r2 = *(const f32x4*)(P + 2436 + ochB);
      const f32x4 a = acc[ptc][ct];
#pragma unroll
      for (int r = 0; r < 4; ++r) {
        const float h = fmaxf(a[r], 0.f);
        a0 += h * r0[r]; a1 += h * r1[r]; a2 += h * r2[r];
      }
    }
    a0 += __shfl_xor(a0, 16); a0 += __shfl_xor(a0, 32);
    a1 += __shfl_xor(a1, 16); a1 += __shfl_xor(a1, 32);
    a2 += __shfl_xor(a2, 16); a2 += __shfl_xor(a2, 32);
    if (kg == 0) {
      float4 o;
      o.x = a0 + P[2500]; o.y = a1 + P[2501]; o.z = a2 + P[2502]; o.w = sig[ptc];
      *(float4*)(out + (base + wbase + ptc * 16 + c) * 4) = o;
    }
  }
}

extern "C" void kernel_launch(void* const* d_in, const int* in_sizes, int n_in,
                              void* d_out, int out_size, void* d_ws, size_t ws_size,
                              hipStream_t stream) {
  Ptrs ptrs;
  for (int i = 0; i < 29; ++i) ptrs.p[i] = (const float*)d_in[i];
  char* ws = (char*)d_ws;
  nerf_prep<<<513, 256, 0, stream>>>(ptrs, ws);
  nerf_main<<<512, 512, 0, stream>>>((const float*)d_in[0], (const float*)d_in[2],
                                     ws, (float*)d_out);
}